// Round 4
// baseline (3696.228 us; speedup 1.0000x reference)
//
#include <hip/hip_runtime.h>

#define T_STEPS 512
#define BATCH 64
#define FDIM 256
#define HDIM 1024
#define CDIM 257
#define GOLD 0x9E3779B9u

typedef __attribute__((ext_vector_type(8))) short short8;
typedef __attribute__((ext_vector_type(4))) short short4_t;
typedef __attribute__((ext_vector_type(4))) float float4_t;
typedef __attribute__((ext_vector_type(4))) int int4_t;

__device__ __forceinline__ short f2bf(float f) {
  unsigned u = __builtin_bit_cast(unsigned, f);
  unsigned r = (u + 0x7fffu + ((u >> 16) & 1u)) >> 16;   // RNE
  return (short)(r & 0xffffu);
}

__device__ __forceinline__ float sigmoid_f(float x) {
  return 1.0f / (1.0f + __expf(-x));
}
__device__ __forceinline__ float tanh_f(float x) {
  float s = __expf(-2.0f * fabsf(x));
  float t = (1.0f - s) / (1.0f + s);
  return (x < 0.0f) ? -t : t;
}

// One LL poll attempt: 16 x 16B coherent loads (8 frag-pairs, each 32B of
// {d, d^H, d, d^H}), single waitcnt. Returns packets in L[16].
__device__ __forceinline__ void ll_load16(const unsigned* base, int4_t (&L)[16]) {
  asm volatile(
    "global_load_dwordx4 %0, %16, off sc0 sc1\n\t"
    "global_load_dwordx4 %1, %16, off offset:16 sc0 sc1\n\t"
    "global_load_dwordx4 %2, %16, off offset:128 sc0 sc1\n\t"
    "global_load_dwordx4 %3, %16, off offset:144 sc0 sc1\n\t"
    "global_load_dwordx4 %4, %16, off offset:256 sc0 sc1\n\t"
    "global_load_dwordx4 %5, %16, off offset:272 sc0 sc1\n\t"
    "global_load_dwordx4 %6, %16, off offset:384 sc0 sc1\n\t"
    "global_load_dwordx4 %7, %16, off offset:400 sc0 sc1\n\t"
    "global_load_dwordx4 %8, %16, off offset:512 sc0 sc1\n\t"
    "global_load_dwordx4 %9, %16, off offset:528 sc0 sc1\n\t"
    "global_load_dwordx4 %10, %16, off offset:640 sc0 sc1\n\t"
    "global_load_dwordx4 %11, %16, off offset:656 sc0 sc1\n\t"
    "global_load_dwordx4 %12, %16, off offset:768 sc0 sc1\n\t"
    "global_load_dwordx4 %13, %16, off offset:784 sc0 sc1\n\t"
    "global_load_dwordx4 %14, %16, off offset:896 sc0 sc1\n\t"
    "global_load_dwordx4 %15, %16, off offset:912 sc0 sc1\n\t"
    "s_waitcnt vmcnt(0)"
    : "=&v"(L[0]), "=&v"(L[1]), "=&v"(L[2]), "=&v"(L[3]),
      "=&v"(L[4]), "=&v"(L[5]), "=&v"(L[6]), "=&v"(L[7]),
      "=&v"(L[8]), "=&v"(L[9]), "=&v"(L[10]), "=&v"(L[11]),
      "=&v"(L[12]), "=&v"(L[13]), "=&v"(L[14]), "=&v"(L[15])
    : "v"(base)
    : "memory");
}

// ---------------------------------------------------------------------------
// prep: fco fp32 -> bf16 (padded to 272 rows), zero LL h double-buffer.
// Zero is a valid epoch-0 packet: {0, 0^hash(0)} = {0,0} since hash(0)=0.
// grid: 272 x 256
// ---------------------------------------------------------------------------
__global__ void prep_kernel(const float* __restrict__ fco_w,
                            short* __restrict__ fcob,
                            unsigned* __restrict__ hll)
{
  const int tid = blockIdx.x * 256 + threadIdx.x;
  {
    const int idx = tid * 4;
    const int c = idx >> 10, k = idx & 1023;
    short4_t o;
    if (c < CDIM) {
      const float4_t f = *(const float4_t*)(fco_w + c * HDIM + k);
      o[0] = f2bf(f[0]); o[1] = f2bf(f[1]); o[2] = f2bf(f[2]); o[3] = f2bf(f[3]);
    } else {
      o[0] = 0; o[1] = 0; o[2] = 0; o[3] = 0;
    }
    *(short4_t*)(fcob + idx) = o;
  }
  if (tid < 32768) {   // 2 parities * 64 rows * 512 pairs * 8B = 512 KiB
    int4_t z = (int4_t){0, 0, 0, 0};
    *(int4_t*)(hll + tid * 4) = z;
  }
}

// ---------------------------------------------------------------------------
// persistent LSTM kernel: 256 WGs = 64 col-groups x 4 batch-quarters.
// Cross-WG exchange: checksum-LL packets {d, d^hash(epoch)} through the LIC.
// Producer: one fire-and-forget 16B sc0sc1 store. Consumer: poll-loads its
// full B-fragment set, validates every dword-pair checksum, retries on miss.
// Correct under arbitrary 4B-granularity tearing: a stale-data dword can only
// pass validation against a fresh checksum if the data is bit-identical.
// ---------------------------------------------------------------------------
__global__ __launch_bounds__(256, 1) void lstm_kernel(
    const float* __restrict__ x,
    const float* __restrict__ wfx, const float* __restrict__ wix,
    const float* __restrict__ wox, const float* __restrict__ wcx,
    const float* __restrict__ bfx, const float* __restrict__ bix,
    const float* __restrict__ box, const float* __restrict__ bcx,
    const float* __restrict__ wfh, const float* __restrict__ wih,
    const float* __restrict__ woh, const float* __restrict__ wch,
    short* __restrict__ hs, unsigned* __restrict__ hll)
{
  const int tid  = threadIdx.x;
  const int lane = tid & 63;
  const int w    = tid >> 6;      // wave id == K-chunk id
  const int quad = lane >> 4;
  const int lm   = lane & 15;
  const int cg   = blockIdx.x & 63;   // column group (16 h-cols)
  const int bq   = blockIdx.x >> 6;   // batch quarter (16 rows)

  // zbuf[parity][slot = w*4+g][b(16) stride 20][i-quad 4]  (fp32, b128-aligned)
  __shared__ float zbuf[2][16 * 320];

  const float* Wh[4] = {wfh, wih, woh, wch};
  const float* Wx[4] = {wfx, wix, wox, wcx};
  const float* Bx[4] = {bfx, bix, box, bcx};

  // ---- preload weight A-fragments (bf16), K-split by wave ----
  short8 wr[4][8];   // recurrent: gate g, local k-tile (global kt = w*8+ktl)
  short8 wxf[4][2];  // input proj: gate g, local k-tile
#pragma unroll
  for (int g = 0; g < 4; ++g) {
    const float* rw = Wh[g] + (cg * 16 + lm) * HDIM;
#pragma unroll
    for (int ktl = 0; ktl < 8; ++ktl) {
      const float* pk = rw + (w * 8 + ktl) * 32 + quad * 8;
      short8 a;
#pragma unroll
      for (int j = 0; j < 8; ++j) a[j] = f2bf(pk[j]);
      wr[g][ktl] = a;
    }
    const float* rx = Wx[g] + (cg * 16 + lm) * FDIM;
#pragma unroll
    for (int ktl = 0; ktl < 2; ++ktl) {
      const float* pk = rx + (w * 2 + ktl) * 32 + quad * 8;
      short8 a;
#pragma unroll
      for (int j = 0; j < 8; ++j) a[j] = f2bf(pk[j]);
      wxf[g][ktl] = a;
    }
  }

  // wave0 epilogue state
  float4_t biasv[4];
  float cst[4] = {0.f, 0.f, 0.f, 0.f};
  {
    const int i4 = lane >> 4;
#pragma unroll
    for (int g = 0; g < 4; ++g) {
#pragma unroll
      for (int r = 0; r < 4; ++r)
        biasv[g][r] = Bx[g][cg * 16 + i4 * 4 + r];
    }
  }

  const int myrow = bq * 16 + lm;

  for (int t = 0; t < T_STEPS; ++t) {
    const int p   = t & 1;
    const int par = p ^ 1;                       // parity holding h(t-1)
    const unsigned Hw = (unsigned)t * GOLD;      // expected checksum key

    // ---- x projection: off the critical path (no h dependency) ----
    float4_t xf[2][2];
    {
      const float* xb = x + ((t * BATCH) + bq * 16 + lm) * FDIM;
#pragma unroll
      for (int i = 0; i < 2; ++i) {
        const float* pk = xb + (w * 2 + i) * 32 + quad * 8;
        xf[i][0] = *(const float4_t*)(pk);
        xf[i][1] = *(const float4_t*)(pk + 4);
      }
    }
    short8 bx[2];
#pragma unroll
    for (int i = 0; i < 2; ++i) {
      short8 a;
      a[0] = f2bf(xf[i][0][0]); a[1] = f2bf(xf[i][0][1]);
      a[2] = f2bf(xf[i][0][2]); a[3] = f2bf(xf[i][0][3]);
      a[4] = f2bf(xf[i][1][0]); a[5] = f2bf(xf[i][1][1]);
      a[6] = f2bf(xf[i][1][2]); a[7] = f2bf(xf[i][1][3]);
      bx[i] = a;
    }
    float4_t acc[4];
#pragma unroll
    for (int g = 0; g < 4; ++g) acc[g] = (float4_t){0.f, 0.f, 0.f, 0.f};
#pragma unroll
    for (int i = 0; i < 2; ++i) {
#pragma unroll
      for (int g = 0; g < 4; ++g)
        acc[g] = __builtin_amdgcn_mfma_f32_16x16x32_bf16(wxf[g][i], bx[i], acc[g], 0, 0, 0);
    }

    // ---- LL poll: load h(t-1) packets until every checksum validates ----
    int4_t L[16];
    {
      const unsigned* base = hll + ((unsigned)((par * 64 + myrow) * 512
                                               + w * 128 + quad * 4) << 1);
      for (;;) {
        ll_load16(base, L);
        int ok = 1;
#pragma unroll
        for (int i = 0; i < 16; ++i)
          ok &= (L[i][1] == (int)(((unsigned)L[i][0]) ^ Hw))
              & (L[i][3] == (int)(((unsigned)L[i][2]) ^ Hw));
        if (__all(ok)) break;
      }
    }

    // ---- extract B-frags and run the recurrent MFMAs ----
#pragma unroll
    for (int ktl = 0; ktl < 8; ++ktl) {
      int4_t v;
      v[0] = L[2 * ktl][0];     v[1] = L[2 * ktl][2];
      v[2] = L[2 * ktl + 1][0]; v[3] = L[2 * ktl + 1][2];
      const short8 bh = __builtin_bit_cast(short8, v);
#pragma unroll
      for (int g = 0; g < 4; ++g)
        acc[g] = __builtin_amdgcn_mfma_f32_16x16x32_bf16(wr[g][ktl], bh, acc[g], 0, 0, 0);
    }

    // partial z (K-chunk) -> LDS. D rows = quad*4+r (i), cols = lm (b).
#pragma unroll
    for (int g = 0; g < 4; ++g)
      *(float4_t*)(&zbuf[p][(w * 4 + g) * 320 + lm * 20 + quad * 4]) = acc[g];

    __syncthreads();

    if (w == 0) {
      const int b = lane & 15, i4 = lane >> 4;   // cell (i = i4*4+r, b)
      const float* zb = &zbuf[p][b * 20 + i4 * 4];
      float4_t zs[4];
#pragma unroll
      for (int g = 0; g < 4; ++g) {
        float4_t v0 = *(const float4_t*)(zb + (0  + g) * 320);
        float4_t v1 = *(const float4_t*)(zb + (4  + g) * 320);
        float4_t v2 = *(const float4_t*)(zb + (8  + g) * 320);
        float4_t v3 = *(const float4_t*)(zb + (12 + g) * 320);
        zs[g] = (v0 + v1) + (v2 + v3) + biasv[g];
      }
      unsigned hv[4];
#pragma unroll
      for (int r = 0; r < 4; ++r) {
        float ff = sigmoid_f(zs[0][r]);
        float ii = sigmoid_f(zs[1][r]);
        float oo = sigmoid_f(zs[2][r]);
        float aa = tanh_f(zs[3][r]);
        float cn = ii * aa + ff * cst[r];
        cst[r] = cn;
        hv[r] = (unsigned)(unsigned short)f2bf(oo * tanh_f(cn));
      }
      const int bg = bq * 16 + b;
      // checksum-LL packet {d0, d0^Hp, d1, d1^Hp}: fire-and-forget 16B store
      {
        const unsigned Hp = (unsigned)(t + 1) * GOLD;
        const unsigned d0 = hv[0] | (hv[1] << 16);
        const unsigned d1 = hv[2] | (hv[3] << 16);
        int4_t pkt;
        pkt[0] = (int)d0;
        pkt[1] = (int)(d0 ^ Hp);
        pkt[2] = (int)d1;
        pkt[3] = (int)(d1 ^ Hp);
        unsigned* hp = hll + ((unsigned)((p * 64 + bg) * 512
                                         + cg * 8 + i4 * 2) << 1);
        asm volatile("global_store_dwordx4 %0, %1, off sc0 sc1"
                     :: "v"(hp), "v"(pkt) : "memory");
      }
      // history for the output projection (plain store, off critical path)
      {
        short4_t h4;
        h4[0] = (short)hv[0]; h4[1] = (short)hv[1];
        h4[2] = (short)hv[2]; h4[3] = (short)hv[3];
        *(short4_t*)(hs + ((t * BATCH) + bg) * HDIM + cg * 16 + i4 * 4) = h4;
      }
    }
  }
}

// ---------------------------------------------------------------------------
// output projection: out[m][c] = sum_k hs[m][k]*fco[c][k] + bias[c]
// ---------------------------------------------------------------------------
__global__ __launch_bounds__(256, 2) void outproj_kernel(
    const short* __restrict__ hs,
    const short* __restrict__ fcob,
    const float* __restrict__ fco_bias,
    float* __restrict__ out)
{
  const int tid = threadIdx.x, lane = tid & 63, w = tid >> 6;
  const int quad = lane >> 4, lm = lane & 15;
  const int blk = blockIdx.x;

  short8 afr[32];
  const short* ar = hs + (blk * 64 + w * 16 + lm) * HDIM;
#pragma unroll
  for (int kt = 0; kt < 32; ++kt)
    afr[kt] = *(const short8*)(ar + kt * 32 + quad * 8);

  for (int nt = 0; nt < 17; ++nt) {
    float4_t a0 = (float4_t){0.f,0.f,0.f,0.f}, a1 = (float4_t){0.f,0.f,0.f,0.f};
    const short* br = fcob + (nt * 16 + lm) * HDIM + quad * 8;
#pragma unroll
    for (int kt = 0; kt < 32; kt += 2) {
      short8 b0 = *(const short8*)(br + kt * 32);
      a0 = __builtin_amdgcn_mfma_f32_16x16x32_bf16(afr[kt], b0, a0, 0, 0, 0);
      short8 b1 = *(const short8*)(br + (kt + 1) * 32);
      a1 = __builtin_amdgcn_mfma_f32_16x16x32_bf16(afr[kt + 1], b1, a1, 0, 0, 0);
    }
    const int c = nt * 16 + lm;
    if (c < CDIM) {
      const float bias = fco_bias[c];
      const int mb = blk * 64 + w * 16 + quad * 4;
#pragma unroll
      for (int r = 0; r < 4; ++r)
        out[(mb + r) * CDIM + c] = a0[r] + a1[r] + bias;
    }
  }
}

// ---------------------------------------------------------------------------
extern "C" void kernel_launch(void* const* d_in, const int* in_sizes, int n_in,
                              void* d_out, int out_size, void* d_ws, size_t ws_size,
                              hipStream_t stream) {
  (void)in_sizes; (void)n_in; (void)out_size; (void)ws_size;
  const float* x     = (const float*)d_in[0];
  const float* wfx_w = (const float*)d_in[1];
  const float* wfx_b = (const float*)d_in[2];
  const float* wix_w = (const float*)d_in[3];
  const float* wix_b = (const float*)d_in[4];
  const float* wox_w = (const float*)d_in[5];
  const float* wox_b = (const float*)d_in[6];
  const float* wcx_w = (const float*)d_in[7];
  const float* wcx_b = (const float*)d_in[8];
  const float* wfh_w = (const float*)d_in[9];
  const float* wih_w = (const float*)d_in[10];
  const float* woh_w = (const float*)d_in[11];
  const float* wch_w = (const float*)d_in[12];
  const float* fco_w = (const float*)d_in[13];
  const float* fco_b = (const float*)d_in[14];
  float* out = (float*)d_out;

  char* ws = (char*)d_ws;
  short*    hs   = (short*)(ws);                         // 67,108,864 B
  short*    fcob = (short*)(ws + 67108864);              //    557,056 B
  unsigned* hll  = (unsigned*)(ws + 67108864 + 557056);  //    524,288 B (LL 2x64x512x8B)

  prep_kernel<<<272, 256, 0, stream>>>(fco_w, fcob, hll);
  lstm_kernel<<<256, 256, 0, stream>>>(x,
                                       wfx_w, wix_w, wox_w, wcx_w,
                                       wfx_b, wix_b, wox_b, wcx_b,
                                       wfh_w, wih_w, woh_w, wch_w,
                                       hs, hll);
  outproj_kernel<<<512, 256, 0, stream>>>(hs, fcob, fco_b, out);
}

// Round 5
// 3062.894 us; speedup vs baseline: 1.2068x; 1.2068x over previous
//
#include <hip/hip_runtime.h>

#define T_STEPS 512
#define BATCH 64
#define FDIM 256
#define HDIM 1024
#define CDIM 257
#define GOLD 0x9E3779B9u

typedef __attribute__((ext_vector_type(8))) short short8;
typedef __attribute__((ext_vector_type(4))) short short4_t;
typedef __attribute__((ext_vector_type(4))) float float4_t;
typedef __attribute__((ext_vector_type(4))) int int4_t;
typedef __attribute__((ext_vector_type(2))) int int2_t;

__device__ __forceinline__ short f2bf(float f) {
  unsigned u = __builtin_bit_cast(unsigned, f);
  unsigned r = (u + 0x7fffu + ((u >> 16) & 1u)) >> 16;   // RNE
  return (short)(r & 0xffffu);
}

__device__ __forceinline__ float sigmoid_f(float x) {
  return 1.0f / (1.0f + __expf(-x));
}
__device__ __forceinline__ float tanh_f(float x) {
  float s = __expf(-2.0f * fabsf(x));
  float t = (1.0f - s) / (1.0f + s);
  return (x < 0.0f) ? -t : t;
}

// Canary: one 8B coherent load {d, d^H}.
__device__ __forceinline__ int2_t ll_load2(const unsigned* p) {
  int2_t r;
  asm volatile("global_load_dwordx2 %0, %1, off sc0 sc1\n\t"
               "s_waitcnt vmcnt(0)"
               : "=&v"(r) : "v"(p) : "memory");
  return r;
}

// Bulk: 16 x 16B coherent loads (8 frag-pairs of {d,d^H,d,d^H}), one waitcnt.
__device__ __forceinline__ void ll_load16(const unsigned* base, int4_t (&L)[16]) {
  asm volatile(
    "global_load_dwordx4 %0, %16, off sc0 sc1\n\t"
    "global_load_dwordx4 %1, %16, off offset:16 sc0 sc1\n\t"
    "global_load_dwordx4 %2, %16, off offset:128 sc0 sc1\n\t"
    "global_load_dwordx4 %3, %16, off offset:144 sc0 sc1\n\t"
    "global_load_dwordx4 %4, %16, off offset:256 sc0 sc1\n\t"
    "global_load_dwordx4 %5, %16, off offset:272 sc0 sc1\n\t"
    "global_load_dwordx4 %6, %16, off offset:384 sc0 sc1\n\t"
    "global_load_dwordx4 %7, %16, off offset:400 sc0 sc1\n\t"
    "global_load_dwordx4 %8, %16, off offset:512 sc0 sc1\n\t"
    "global_load_dwordx4 %9, %16, off offset:528 sc0 sc1\n\t"
    "global_load_dwordx4 %10, %16, off offset:640 sc0 sc1\n\t"
    "global_load_dwordx4 %11, %16, off offset:656 sc0 sc1\n\t"
    "global_load_dwordx4 %12, %16, off offset:768 sc0 sc1\n\t"
    "global_load_dwordx4 %13, %16, off offset:784 sc0 sc1\n\t"
    "global_load_dwordx4 %14, %16, off offset:896 sc0 sc1\n\t"
    "global_load_dwordx4 %15, %16, off offset:912 sc0 sc1\n\t"
    "s_waitcnt vmcnt(0)"
    : "=&v"(L[0]), "=&v"(L[1]), "=&v"(L[2]), "=&v"(L[3]),
      "=&v"(L[4]), "=&v"(L[5]), "=&v"(L[6]), "=&v"(L[7]),
      "=&v"(L[8]), "=&v"(L[9]), "=&v"(L[10]), "=&v"(L[11]),
      "=&v"(L[12]), "=&v"(L[13]), "=&v"(L[14]), "=&v"(L[15])
    : "v"(base)
    : "memory");
}

// ---------------------------------------------------------------------------
// prep: fco fp32 -> bf16 (padded to 272 rows), zero LL h double-buffer.
// Zero is a valid epoch-0 packet since hash(0)=0. grid: 272 x 256
// ---------------------------------------------------------------------------
__global__ void prep_kernel(const float* __restrict__ fco_w,
                            short* __restrict__ fcob,
                            unsigned* __restrict__ hll)
{
  const int tid = blockIdx.x * 256 + threadIdx.x;
  {
    const int idx = tid * 4;
    const int c = idx >> 10, k = idx & 1023;
    short4_t o;
    if (c < CDIM) {
      const float4_t f = *(const float4_t*)(fco_w + c * HDIM + k);
      o[0] = f2bf(f[0]); o[1] = f2bf(f[1]); o[2] = f2bf(f[2]); o[3] = f2bf(f[3]);
    } else {
      o[0] = 0; o[1] = 0; o[2] = 0; o[3] = 0;
    }
    *(short4_t*)(fcob + idx) = o;
  }
  if (tid < 32768) {   // 2 parities * 64 rows * 512 pairs * 8B = 512 KiB
    int4_t z = (int4_t){0, 0, 0, 0};
    *(int4_t*)(hll + tid * 4) = z;
  }
}

// ---------------------------------------------------------------------------
// persistent LSTM: 128 WGs = 32 col-groups (32 cols) x 4 batch-quarters.
// Exchange: checksum-LL {d, d^hash(epoch)} via LIC. Producer: fire-and-forget
// 16B stores. Consumer: (1) cheap canary poll (8B/lane, 4 sample lanes per
// producer-wave), (2) one bulk load + full checksum validation (rare retry).
// 32 cols/WG halves broadcast amplification vs 16-col WGs (8 MB/step reads).
// ---------------------------------------------------------------------------
__global__ __launch_bounds__(256, 1) void lstm_kernel(
    const float* __restrict__ x,
    const float* __restrict__ wfx, const float* __restrict__ wix,
    const float* __restrict__ wox, const float* __restrict__ wcx,
    const float* __restrict__ bfx, const float* __restrict__ bix,
    const float* __restrict__ box, const float* __restrict__ bcx,
    const float* __restrict__ wfh, const float* __restrict__ wih,
    const float* __restrict__ woh, const float* __restrict__ wch,
    short* __restrict__ hs, unsigned* __restrict__ hll)
{
  const int tid  = threadIdx.x;
  const int lane = tid & 63;
  const int w    = tid >> 6;      // wave id == K-chunk id (256 K each)
  const int quad = lane >> 4;
  const int lm   = lane & 15;
  const int cg   = blockIdx.x & 31;   // column group (32 h-cols)
  const int bq   = blockIdx.x >> 5;   // batch quarter (16 rows)

  // zbuf[parity][slot = w*8 + mt*4 + g][b(16) stride 20][i-quad 4]
  __shared__ float zbuf[2][32 * 320];   // 80 KiB

  const float* Wh[4] = {wfh, wih, woh, wch};
  const float* Wx[4] = {wfx, wix, wox, wcx};
  const float* Bx[4] = {bfx, bix, box, bcx};

  // ---- preload weight A-fragments (bf16): 2 m-tiles x 4 gates ----
  // A[m = lm -> col cg*32+mt*16+lm][k = quad*8 + j]
  short8 wr[2][4][8];   // recurrent, K = w*256 + ktl*32
  short8 wxf[2][4][2];  // input proj, K = w*64 + i*32
#pragma unroll
  for (int g = 0; g < 4; ++g) {
#pragma unroll
    for (int mt = 0; mt < 2; ++mt) {
      const float* rw = Wh[g] + (cg * 32 + mt * 16 + lm) * HDIM;
#pragma unroll
      for (int ktl = 0; ktl < 8; ++ktl) {
        const float* pk = rw + w * 256 + ktl * 32 + quad * 8;
        short8 a;
#pragma unroll
        for (int j = 0; j < 8; ++j) a[j] = f2bf(pk[j]);
        wr[mt][g][ktl] = a;
      }
      const float* rx = Wx[g] + (cg * 32 + mt * 16 + lm) * FDIM;
#pragma unroll
      for (int i = 0; i < 2; ++i) {
        const float* pk = rx + w * 64 + i * 32 + quad * 8;
        short8 a;
#pragma unroll
        for (int j = 0; j < 8; ++j) a[j] = f2bf(pk[j]);
        wxf[mt][g][i] = a;
      }
    }
  }

  // epilogue state (waves 0,1; wave e handles m-tile e)
  float4_t biasv[4];
  float cst[4] = {0.f, 0.f, 0.f, 0.f};
  if (w < 2) {
    const int i4 = lane >> 4;
#pragma unroll
    for (int g = 0; g < 4; ++g) {
#pragma unroll
      for (int r = 0; r < 4; ++r)
        biasv[g][r] = Bx[g][cg * 32 + w * 16 + i4 * 4 + r];
    }
  }

  // canary mapping: 16 producer-waves feed this consumer wave's K-chunk
  // (cgs [w*8, w*8+8) x epilogue-waves {0,1}); 4 sample lanes each.
  const int pw  = lane & 15;           // producer-wave index
  const int cs  = lane >> 4;           // canary slot 0..3
  const int cgp = w * 8 + (pw >> 1);
  const int ep  = pw & 1;
  const int crow  = bq * 16 + cs * 4;              // producer lane b = cs*4
  const int cpair = cgp * 16 + ep * 8 + cs * 2;    // producer lane i4 = cs
  const int myrow = bq * 16 + lm;

  for (int t = 0; t < T_STEPS; ++t) {
    const int p   = t & 1;
    const int par = p ^ 1;                       // parity holding h(t-1)
    const unsigned Hw = (unsigned)t * GOLD;      // expected checksum key

    // ---- x projection: off the critical path (no h dependency) ----
    float4_t xf[2][2];
    {
      const float* xb = x + ((t * BATCH) + bq * 16 + lm) * FDIM;
#pragma unroll
      for (int i = 0; i < 2; ++i) {
        const float* pk = xb + w * 64 + i * 32 + quad * 8;
        xf[i][0] = *(const float4_t*)(pk);
        xf[i][1] = *(const float4_t*)(pk + 4);
      }
    }
    short8 bx[2];
#pragma unroll
    for (int i = 0; i < 2; ++i) {
      short8 a;
      a[0] = f2bf(xf[i][0][0]); a[1] = f2bf(xf[i][0][1]);
      a[2] = f2bf(xf[i][0][2]); a[3] = f2bf(xf[i][0][3]);
      a[4] = f2bf(xf[i][1][0]); a[5] = f2bf(xf[i][1][1]);
      a[6] = f2bf(xf[i][1][2]); a[7] = f2bf(xf[i][1][3]);
      bx[i] = a;
    }
    float4_t acc[2][4];
#pragma unroll
    for (int mt = 0; mt < 2; ++mt)
#pragma unroll
      for (int g = 0; g < 4; ++g) acc[mt][g] = (float4_t){0.f, 0.f, 0.f, 0.f};
#pragma unroll
    for (int i = 0; i < 2; ++i)
#pragma unroll
      for (int mt = 0; mt < 2; ++mt)
#pragma unroll
        for (int g = 0; g < 4; ++g)
          acc[mt][g] = __builtin_amdgcn_mfma_f32_16x16x32_bf16(
              wxf[mt][g][i], bx[i], acc[mt][g], 0, 0, 0);

    // ---- phase 1: canary poll (8B/lane/attempt) ----
    {
      const unsigned* ca = hll + (((unsigned)(par * 64 + crow) * 512 + cpair) << 1);
      for (;;) {
        int2_t c = ll_load2(ca);
        if (__all((int)(((unsigned)c[1]) == (((unsigned)c[0]) ^ Hw)))) break;
      }
    }

    // ---- phase 2: bulk load h(t-1) once, validate all checksums ----
    int4_t L[16];
    {
      const unsigned* base = hll + (((unsigned)(par * 64 + myrow) * 512
                                     + w * 128 + quad * 4) << 1);
      for (;;) {
        ll_load16(base, L);
        int ok = 1;
#pragma unroll
        for (int i = 0; i < 16; ++i)
          ok &= (L[i][1] == (int)(((unsigned)L[i][0]) ^ Hw))
              & (L[i][3] == (int)(((unsigned)L[i][2]) ^ Hw));
        if (__all(ok)) break;
      }
    }

    // ---- recurrent MFMAs ----
#pragma unroll
    for (int ktl = 0; ktl < 8; ++ktl) {
      int4_t v;
      v[0] = L[2 * ktl][0];     v[1] = L[2 * ktl][2];
      v[2] = L[2 * ktl + 1][0]; v[3] = L[2 * ktl + 1][2];
      const short8 bh = __builtin_bit_cast(short8, v);
#pragma unroll
      for (int mt = 0; mt < 2; ++mt)
#pragma unroll
        for (int g = 0; g < 4; ++g)
          acc[mt][g] = __builtin_amdgcn_mfma_f32_16x16x32_bf16(
              wr[mt][g][ktl], bh, acc[mt][g], 0, 0, 0);
    }

    // partial z -> LDS
#pragma unroll
    for (int mt = 0; mt < 2; ++mt)
#pragma unroll
      for (int g = 0; g < 4; ++g)
        *(float4_t*)(&zbuf[p][(w * 8 + mt * 4 + g) * 320 + lm * 20 + quad * 4])
            = acc[mt][g];

    __syncthreads();

    if (w < 2) {   // epilogue wave e = w handles m-tile e (16 cols)
      const int e = w;
      const int b = lane & 15, i4 = lane >> 4;   // cell (i = i4*4+r, b)
      const float* zb = &zbuf[p][b * 20 + i4 * 4];
      float4_t zs[4];
#pragma unroll
      for (int g = 0; g < 4; ++g) {
        float4_t v0 = *(const float4_t*)(zb + (0  + e * 4 + g) * 320);
        float4_t v1 = *(const float4_t*)(zb + (8  + e * 4 + g) * 320);
        float4_t v2 = *(const float4_t*)(zb + (16 + e * 4 + g) * 320);
        float4_t v3 = *(const float4_t*)(zb + (24 + e * 4 + g) * 320);
        zs[g] = (v0 + v1) + (v2 + v3) + biasv[g];
      }
      unsigned hv[4];
#pragma unroll
      for (int r = 0; r < 4; ++r) {
        float ff = sigmoid_f(zs[0][r]);
        float ii = sigmoid_f(zs[1][r]);
        float oo = sigmoid_f(zs[2][r]);
        float aa = tanh_f(zs[3][r]);
        float cn = ii * aa + ff * cst[r];
        cst[r] = cn;
        hv[r] = (unsigned)(unsigned short)f2bf(oo * tanh_f(cn));
      }
      const int bg = bq * 16 + b;
      {
        const unsigned Hp = (unsigned)(t + 1) * GOLD;
        const unsigned d0 = hv[0] | (hv[1] << 16);
        const unsigned d1 = hv[2] | (hv[3] << 16);
        int4_t pkt;
        pkt[0] = (int)d0;
        pkt[1] = (int)(d0 ^ Hp);
        pkt[2] = (int)d1;
        pkt[3] = (int)(d1 ^ Hp);
        unsigned* hp = hll + (((unsigned)(p * 64 + bg) * 512
                               + cg * 16 + e * 8 + i4 * 2) << 1);
        asm volatile("global_store_dwordx4 %0, %1, off sc0 sc1"
                     :: "v"(hp), "v"(pkt) : "memory");
      }
      {
        short4_t h4;
        h4[0] = (short)hv[0]; h4[1] = (short)hv[1];
        h4[2] = (short)hv[2]; h4[3] = (short)hv[3];
        *(short4_t*)(hs + ((t * BATCH) + bg) * HDIM
                     + cg * 32 + e * 16 + i4 * 4) = h4;
      }
    }
  }
}

// ---------------------------------------------------------------------------
// output projection: out[m][c] = sum_k hs[m][k]*fco[c][k] + bias[c]
// ---------------------------------------------------------------------------
__global__ __launch_bounds__(256, 2) void outproj_kernel(
    const short* __restrict__ hs,
    const short* __restrict__ fcob,
    const float* __restrict__ fco_bias,
    float* __restrict__ out)
{
  const int tid = threadIdx.x, lane = tid & 63, w = tid >> 6;
  const int quad = lane >> 4, lm = lane & 15;
  const int blk = blockIdx.x;

  short8 afr[32];
  const short* ar = hs + (blk * 64 + w * 16 + lm) * HDIM;
#pragma unroll
  for (int kt = 0; kt < 32; ++kt)
    afr[kt] = *(const short8*)(ar + kt * 32 + quad * 8);

  for (int nt = 0; nt < 17; ++nt) {
    float4_t a0 = (float4_t){0.f,0.f,0.f,0.f}, a1 = (float4_t){0.f,0.f,0.f,0.f};
    const short* br = fcob + (nt * 16 + lm) * HDIM + quad * 8;
#pragma unroll
    for (int kt = 0; kt < 32; kt += 2) {
      short8 b0 = *(const short8*)(br + kt * 32);
      a0 = __builtin_amdgcn_mfma_f32_16x16x32_bf16(afr[kt], b0, a0, 0, 0, 0);
      short8 b1 = *(const short8*)(br + (kt + 1) * 32);
      a1 = __builtin_amdgcn_mfma_f32_16x16x32_bf16(afr[kt + 1], b1, a1, 0, 0, 0);
    }
    const int c = nt * 16 + lm;
    if (c < CDIM) {
      const float bias = fco_bias[c];
      const int mb = blk * 64 + w * 16 + quad * 4;
#pragma unroll
      for (int r = 0; r < 4; ++r)
        out[(mb + r) * CDIM + c] = a0[r] + a1[r] + bias;
    }
  }
}

// ---------------------------------------------------------------------------
extern "C" void kernel_launch(void* const* d_in, const int* in_sizes, int n_in,
                              void* d_out, int out_size, void* d_ws, size_t ws_size,
                              hipStream_t stream) {
  (void)in_sizes; (void)n_in; (void)out_size; (void)ws_size;
  const float* x     = (const float*)d_in[0];
  const float* wfx_w = (const float*)d_in[1];
  const float* wfx_b = (const float*)d_in[2];
  const float* wix_w = (const float*)d_in[3];
  const float* wix_b = (const float*)d_in[4];
  const float* wox_w = (const float*)d_in[5];
  const float* wox_b = (const float*)d_in[6];
  const float* wcx_w = (const float*)d_in[7];
  const float* wcx_b = (const float*)d_in[8];
  const float* wfh_w = (const float*)d_in[9];
  const float* wih_w = (const float*)d_in[10];
  const float* woh_w = (const float*)d_in[11];
  const float* wch_w = (const float*)d_in[12];
  const float* fco_w = (const float*)d_in[13];
  const float* fco_b = (const float*)d_in[14];
  float* out = (float*)d_out;

  char* ws = (char*)d_ws;
  short*    hs   = (short*)(ws);                         // 67,108,864 B
  short*    fcob = (short*)(ws + 67108864);              //    557,056 B
  unsigned* hll  = (unsigned*)(ws + 67108864 + 557056);  //    524,288 B

  prep_kernel<<<272, 256, 0, stream>>>(fco_w, fcob, hll);
  lstm_kernel<<<128, 256, 0, stream>>>(x,
                                       wfx_w, wix_w, wox_w, wcx_w,
                                       wfx_b, wix_b, wox_b, wcx_b,
                                       wfh_w, wih_w, woh_w, wch_w,
                                       hs, hll);
  outproj_kernel<<<512, 256, 0, stream>>>(hs, fcob, fco_b, out);
}